// Round 1
// baseline (325.176 us; speedup 1.0000x reference)
//
#include <hip/hip_runtime.h>
#include <stdint.h>

// graphConv: out[b] = (sum_k W_k S^k) @ X_b ; B=128, N=1024, D=64, K=8
//
// Chain (depth 3, parallel-batched):
//   U_j = W_{2j} + W_{2j+1} * S   (j=0..3)      } launch 1 (+ S2 = S*S)
//   V0  = U0 + U1 * S2 ; V1 = U2 + U3 * S2      } launch 2 (+ S4 = S2*S2)
//   A   = V0 + V1 * S4                          } launch 3
//   out = A @ X (batched)                       } launch 4
//
// All chain GEMMs use split-bf16 (hi+lo) with 3-term MFMA -> ~fp32 accuracy.
// Apply GEMM is plain bf16 (error ~0.3% rel, within threshold).

#define NN 1024
#define NBATCH 128
#define DDIM 64
#define LDK 72  // 64 + 8 pad (row stride 144B = 9*16B: keeps 16B align, 2-way banks)

typedef float floatx4 __attribute__((ext_vector_type(4)));
typedef __bf16 bf16x8 __attribute__((ext_vector_type(8)));
typedef unsigned short u16;

__device__ __forceinline__ u16 f2bf(float f) {
  union { float f; uint32_t u; } v; v.f = f;
  uint32_t u = v.u;
  return (u16)((u + 0x7fffu + ((u >> 16) & 1u)) >> 16);  // RNE
}
__device__ __forceinline__ float bf2f(u16 h) {
  union { float f; uint32_t u; } v; v.u = ((uint32_t)h) << 16;
  return v.f;
}

// ---------------- split fp32 -> bf16 hi/lo (row-major, optional col-major) --
struct SplitJob {
  const float* src;
  u16* rmHi; u16* rmLo;
  u16* cmHi; u16* cmLo;  // may be null
};
struct SplitJobs { SplitJob j[5]; };

__global__ __launch_bounds__(256) void split_kernel(SplitJobs jobs) {
  SplitJob jb = jobs.j[blockIdx.z];
  int idx4 = blockIdx.x * 256 + threadIdx.x;   // float4 index
  int e = idx4 * 4;
  int row = e >> 10;          // / NN
  int col = e & (NN - 1);
  float4 f = ((const float4*)jb.src)[idx4];
  float fv[4] = {f.x, f.y, f.z, f.w};
  u16 hi[4], lo[4];
#pragma unroll
  for (int i = 0; i < 4; ++i) {
    hi[i] = f2bf(fv[i]);
    lo[i] = f2bf(fv[i] - bf2f(hi[i]));
  }
  uint2 ph, pl;
  ph.x = (uint32_t)hi[0] | ((uint32_t)hi[1] << 16);
  ph.y = (uint32_t)hi[2] | ((uint32_t)hi[3] << 16);
  pl.x = (uint32_t)lo[0] | ((uint32_t)lo[1] << 16);
  pl.y = (uint32_t)lo[2] | ((uint32_t)lo[3] << 16);
  *(uint2*)&jb.rmHi[e] = ph;
  *(uint2*)&jb.rmLo[e] = pl;
  if (jb.cmHi) {
#pragma unroll
    for (int i = 0; i < 4; ++i) {
      jb.cmHi[(size_t)(col + i) * NN + row] = hi[i];
      jb.cmLo[(size_t)(col + i) * NN + row] = lo[i];
    }
  }
}

// ---------------- chain GEMM: out = [add +] Aop * Bop, split-bf16 3-term ----
struct GemmJob {
  const u16* Ahi; const u16* Alo;     // A operand, row-major MxK
  const u16* Bhi; const u16* Blo;     // B operand stored col-major: (k,n) at [n*NN+k]
  const float* addF;                  // optional fp32 additive init
  const u16* addHi; const u16* addLo; // optional split additive init
  u16* outRmHi; u16* outRmLo;         // optional row-major out
  u16* outCmHi; u16* outCmLo;         // optional col-major out
};
struct GemmJobs { GemmJob j[5]; };

__global__ __launch_bounds__(256) void chain_gemm(GemmJobs jobs) {
  GemmJob jb = jobs.j[blockIdx.z];
  __shared__ u16 Al[2][64][LDK];      // [hi/lo][m][k]
  __shared__ u16 Bl[2][64][LDK];      // [hi/lo][n][k]  (B^T)
  const int t = threadIdx.x;
  const int wave = t >> 6, lane = t & 63;
  const int wm = wave >> 1, wn = wave & 1;
  const int lm = lane & 15, q = lane >> 4;
  const int bm = blockIdx.x * 64, bn = blockIdx.y * 64;
  floatx4 acc[2][2] = {};

  for (int kt = 0; kt < NN / 64; ++kt) {
    __syncthreads();
#pragma unroll
    for (int i = 0; i < 2; ++i) {
      int c = t + 256 * i;
      int r = c >> 3, c8 = (c & 7) * 8;
      size_t ga = (size_t)(bm + r) * NN + kt * 64 + c8;
      size_t gb = (size_t)(bn + r) * NN + kt * 64 + c8;
      *(uint4*)&Al[0][r][c8] = *(const uint4*)&jb.Ahi[ga];
      *(uint4*)&Al[1][r][c8] = *(const uint4*)&jb.Alo[ga];
      *(uint4*)&Bl[0][r][c8] = *(const uint4*)&jb.Bhi[gb];
      *(uint4*)&Bl[1][r][c8] = *(const uint4*)&jb.Blo[gb];
    }
    __syncthreads();
#pragma unroll
    for (int ks = 0; ks < 2; ++ks) {
      bf16x8 ah[2], al[2], bh[2], bl[2];
#pragma unroll
      for (int mi = 0; mi < 2; ++mi) {
        ah[mi] = *(const bf16x8*)&Al[0][wm * 32 + mi * 16 + lm][ks * 32 + q * 8];
        al[mi] = *(const bf16x8*)&Al[1][wm * 32 + mi * 16 + lm][ks * 32 + q * 8];
      }
#pragma unroll
      for (int ni = 0; ni < 2; ++ni) {
        bh[ni] = *(const bf16x8*)&Bl[0][wn * 32 + ni * 16 + lm][ks * 32 + q * 8];
        bl[ni] = *(const bf16x8*)&Bl[1][wn * 32 + ni * 16 + lm][ks * 32 + q * 8];
      }
#pragma unroll
      for (int mi = 0; mi < 2; ++mi)
#pragma unroll
        for (int ni = 0; ni < 2; ++ni) {
          acc[mi][ni] = __builtin_amdgcn_mfma_f32_16x16x32_bf16(ah[mi], bh[ni], acc[mi][ni], 0, 0, 0);
          acc[mi][ni] = __builtin_amdgcn_mfma_f32_16x16x32_bf16(ah[mi], bl[ni], acc[mi][ni], 0, 0, 0);
          acc[mi][ni] = __builtin_amdgcn_mfma_f32_16x16x32_bf16(al[mi], bh[ni], acc[mi][ni], 0, 0, 0);
        }
    }
  }

#pragma unroll
  for (int mi = 0; mi < 2; ++mi)
#pragma unroll
    for (int ni = 0; ni < 2; ++ni)
#pragma unroll
      for (int r = 0; r < 4; ++r) {
        int row = bm + wm * 32 + mi * 16 + q * 4 + r;
        int col = bn + wn * 32 + ni * 16 + lm;
        size_t rm = (size_t)row * NN + col;
        float v = acc[mi][ni][r];
        if (jb.addF)  v += jb.addF[rm];
        if (jb.addHi) v += bf2f(jb.addHi[rm]) + bf2f(jb.addLo[rm]);
        u16 h = f2bf(v);
        u16 l = f2bf(v - bf2f(h));
        if (jb.outRmHi) { jb.outRmHi[rm] = h; jb.outRmLo[rm] = l; }
        if (jb.outCmHi) {
          size_t cm = (size_t)col * NN + row;
          jb.outCmHi[cm] = h; jb.outCmLo[cm] = l;
        }
      }
}

// ---------------- apply: out[b] = A @ X_b (plain bf16) ----------------------
__global__ __launch_bounds__(256) void apply_kernel(const u16* __restrict__ Ahi,
                                                    const float* __restrict__ X,
                                                    float* __restrict__ out) {
  __shared__ u16 Al[64][LDK];   // [m][k]
  __shared__ u16 Bl[64][LDK];   // [d][k]  (X_b^T, converted to bf16)
  const int t = threadIdx.x;
  const int wave = t >> 6, lane = t & 63;
  const int wm = wave >> 1, wn = wave & 1;
  const int lm = lane & 15, q = lane >> 4;
  const int bm = blockIdx.x * 64;
  const int b = blockIdx.y;
  floatx4 acc[2][2] = {};

  for (int kt = 0; kt < NN / 64; ++kt) {
    __syncthreads();
#pragma unroll
    for (int i = 0; i < 2; ++i) {
      int c = t + 256 * i;
      int r = c >> 3, c8 = (c & 7) * 8;
      *(uint4*)&Al[r][c8] = *(const uint4*)&Ahi[(size_t)(bm + r) * NN + kt * 64 + c8];
    }
#pragma unroll
    for (int i = 0; i < 4; ++i) {
      int c = t + 256 * i;
      int kr = c >> 4, d4 = (c & 15) * 4;
      float4 f = *(const float4*)&X[((size_t)b * NN + kt * 64 + kr) * DDIM + d4];
      Bl[d4 + 0][kr] = f2bf(f.x);
      Bl[d4 + 1][kr] = f2bf(f.y);
      Bl[d4 + 2][kr] = f2bf(f.z);
      Bl[d4 + 3][kr] = f2bf(f.w);
    }
    __syncthreads();
#pragma unroll
    for (int ks = 0; ks < 2; ++ks) {
      bf16x8 a[2], bb[2];
#pragma unroll
      for (int mi = 0; mi < 2; ++mi)
        a[mi] = *(const bf16x8*)&Al[wm * 32 + mi * 16 + lm][ks * 32 + q * 8];
#pragma unroll
      for (int ni = 0; ni < 2; ++ni)
        bb[ni] = *(const bf16x8*)&Bl[wn * 32 + ni * 16 + lm][ks * 32 + q * 8];
#pragma unroll
      for (int mi = 0; mi < 2; ++mi)
#pragma unroll
        for (int ni = 0; ni < 2; ++ni)
          acc[mi][ni] = __builtin_amdgcn_mfma_f32_16x16x32_bf16(a[mi], bb[ni], acc[mi][ni], 0, 0, 0);
    }
  }

#pragma unroll
  for (int mi = 0; mi < 2; ++mi)
#pragma unroll
    for (int ni = 0; ni < 2; ++ni)
#pragma unroll
      for (int r = 0; r < 4; ++r) {
        int row = bm + wm * 32 + mi * 16 + q * 4 + r;
        int col = wn * 32 + ni * 16 + lm;
        out[((size_t)b * NN + row) * DDIM + col] = acc[mi][ni][r];
      }
}

extern "C" void kernel_launch(void* const* d_in, const int* in_sizes, int n_in,
                              void* d_out, int out_size, void* d_ws, size_t ws_size,
                              hipStream_t stream) {
  const float* nodes  = (const float*)d_in[0];  // [128,1024,64]
  const float* weight = (const float*)d_in[1];  // [8,1024,1024]
  const float* gs     = (const float*)d_in[2];  // [1024,1024]
  float* out = (float*)d_out;
  u16* ws = (u16*)d_ws;
  const size_t MB = (size_t)NN * NN;  // elements per 2MB bf16 buffer
  auto buf = [&](int i) -> u16* { return ws + (size_t)i * MB; };
  // layout: 0,1 S_rm hi/lo | 2,3 S_cm hi/lo | 4..11 W1,W3,W5,W7 rm hi/lo
  // 12..19 U0..U3 rm hi/lo | 20..23 S2 rm+cm hi/lo | 24..27 V0,V1 rm hi/lo
  // 28,29 S4 cm hi/lo | 30,31 A rm hi/lo   (total 64 MB)

  SplitJobs sj{};
  sj.j[0] = { gs,              buf(0),  buf(1),  buf(2), buf(3) };
  sj.j[1] = { weight + 1 * MB, buf(4),  buf(5),  nullptr, nullptr };
  sj.j[2] = { weight + 3 * MB, buf(6),  buf(7),  nullptr, nullptr };
  sj.j[3] = { weight + 5 * MB, buf(8),  buf(9),  nullptr, nullptr };
  sj.j[4] = { weight + 7 * MB, buf(10), buf(11), nullptr, nullptr };
  split_kernel<<<dim3(NN * NN / 1024, 1, 5), 256, 0, stream>>>(sj);

  GemmJobs g1{};
  // S2 = S*S (needs rm+cm out)
  g1.j[0] = { buf(0), buf(1), buf(2), buf(3), nullptr, nullptr, nullptr,
              buf(20), buf(21), buf(22), buf(23) };
  // U_j = W_{2j} + W_{2j+1}*S
  g1.j[1] = { buf(4),  buf(5),  buf(2), buf(3), weight + 0 * MB, nullptr, nullptr,
              buf(12), buf(13), nullptr, nullptr };
  g1.j[2] = { buf(6),  buf(7),  buf(2), buf(3), weight + 2 * MB, nullptr, nullptr,
              buf(14), buf(15), nullptr, nullptr };
  g1.j[3] = { buf(8),  buf(9),  buf(2), buf(3), weight + 4 * MB, nullptr, nullptr,
              buf(16), buf(17), nullptr, nullptr };
  g1.j[4] = { buf(10), buf(11), buf(2), buf(3), weight + 6 * MB, nullptr, nullptr,
              buf(18), buf(19), nullptr, nullptr };
  chain_gemm<<<dim3(16, 16, 5), 256, 0, stream>>>(g1);

  GemmJobs g2{};
  // S4 = S2*S2 (cm out only)
  g2.j[0] = { buf(20), buf(21), buf(22), buf(23), nullptr, nullptr, nullptr,
              nullptr, nullptr, buf(28), buf(29) };
  // V0 = U0 + U1*S2
  g2.j[1] = { buf(14), buf(15), buf(22), buf(23), nullptr, buf(12), buf(13),
              buf(24), buf(25), nullptr, nullptr };
  // V1 = U2 + U3*S2
  g2.j[2] = { buf(18), buf(19), buf(22), buf(23), nullptr, buf(16), buf(17),
              buf(26), buf(27), nullptr, nullptr };
  chain_gemm<<<dim3(16, 16, 3), 256, 0, stream>>>(g2);

  GemmJobs g3{};
  // A = V0 + V1*S4
  g3.j[0] = { buf(26), buf(27), buf(28), buf(29), nullptr, buf(24), buf(25),
              buf(30), buf(31), nullptr, nullptr };
  chain_gemm<<<dim3(16, 16, 1), 256, 0, stream>>>(g3);

  apply_kernel<<<dim3(16, NBATCH), 256, 0, stream>>>(buf(30), nodes, out);
}

// Round 2
// 298.708 us; speedup vs baseline: 1.0886x; 1.0886x over previous
//
#include <hip/hip_runtime.h>
#include <stdint.h>

// graphConv: out[b] = (sum_k W_k S^k) @ X_b ; B=128, N=1024, D=64, K=8
//
// Chain (depth 3, parallel-batched, split-bf16 3-term for ~fp32 accuracy):
//   L1: S2 = S*S ; U_j = W_{2j} + W_{2j+1}*S (j=0..3)     [z=5]
//   L2: S4 = S2*S2 ; V0 = U0 + U1*S2 ; V1 = U2 + U3*S2    [z=3]
//   L3: A  = V0 + V1*S4                                   [z=1]
// Apply: out'[n, b*64+d] = A @ XT  as ONE 1024x8192x1024 bf16 GEMM,
//        XT[b*64+d][k] = X[b][k][d] built by a transpose kernel.
//
// GEMM tiles: 128x128, BK=64, XOR-swizzled unpadded LDS (conflict-free
// ds_read_b128) staged via global_load_lds width=16.

#define NN 1024
#define NBATCH 128
#define DDIM 64

typedef float floatx4 __attribute__((ext_vector_type(4)));
typedef __bf16 bf16x8 __attribute__((ext_vector_type(8)));
typedef unsigned short u16;

__device__ __forceinline__ u16 f2bf(float f) {
  union { float f; uint32_t u; } v; v.f = f;
  uint32_t u = v.u;
  return (u16)((u + 0x7fffu + ((u >> 16) & 1u)) >> 16);  // RNE
}
__device__ __forceinline__ float bf2f(u16 h) {
  union { float f; uint32_t u; } v; v.u = ((uint32_t)h) << 16;
  return v.f;
}

__device__ __forceinline__ void gll16(const void* g, void* l) {
  __builtin_amdgcn_global_load_lds(
      (const __attribute__((address_space(1))) void*)g,
      (__attribute__((address_space(3))) void*)l, 16, 0, 0);
}

// Stage 128 rows x 64 u16 (one 128x64 bf16 tile) row-major from g (row stride
// NN) into 16KB linear LDS, 16B chunks XOR-swizzled by row&7. Wave w stages
// rows w*32..w*32+31. Conflict-free on both write (DMA) and ds_read_b128.
__device__ __forceinline__ void stage_tile(const u16* __restrict__ g, u16* lds,
                                           int wave, int lane) {
  const int r = lane >> 3, c = lane & 7;
  const int sw = (c ^ r) * 8;
#pragma unroll
  for (int i = 0; i < 4; ++i) {
    const int rb = wave * 32 + i * 8;
    gll16(g + (size_t)(rb + r) * NN + sw, lds + rb * 64);
  }
}

// ---------------- split fp32 -> bf16 hi/lo --------------------------------
struct SplitJob {
  const float* src;
  u16* rmHi; u16* rmLo;
  u16* cmHi; u16* cmLo;  // may be null
};
struct SplitJobs { SplitJob j[5]; };

__global__ __launch_bounds__(256) void split_kernel(SplitJobs jobs) {
  SplitJob jb = jobs.j[blockIdx.z];
  int idx4 = blockIdx.x * 256 + threadIdx.x;
  int e = idx4 * 4;
  int row = e >> 10;
  int col = e & (NN - 1);
  float4 f = ((const float4*)jb.src)[idx4];
  float fv[4] = {f.x, f.y, f.z, f.w};
  u16 hi[4], lo[4];
#pragma unroll
  for (int i = 0; i < 4; ++i) {
    hi[i] = f2bf(fv[i]);
    lo[i] = f2bf(fv[i] - bf2f(hi[i]));
  }
  uint2 ph, pl;
  ph.x = (uint32_t)hi[0] | ((uint32_t)hi[1] << 16);
  ph.y = (uint32_t)hi[2] | ((uint32_t)hi[3] << 16);
  pl.x = (uint32_t)lo[0] | ((uint32_t)lo[1] << 16);
  pl.y = (uint32_t)lo[2] | ((uint32_t)lo[3] << 16);
  *(uint2*)&jb.rmHi[e] = ph;
  *(uint2*)&jb.rmLo[e] = pl;
  if (jb.cmHi) {
#pragma unroll
    for (int i = 0; i < 4; ++i) {
      jb.cmHi[(size_t)(col + i) * NN + row] = hi[i];
      jb.cmLo[(size_t)(col + i) * NN + row] = lo[i];
    }
  }
}

// ---------------- transpose X [B,K,D] fp32 -> XT [B*D, K] bf16 -------------
__global__ __launch_bounds__(256) void transpose_x(const float* __restrict__ X,
                                                   u16* __restrict__ XT) {
  __shared__ u16 T[64][72];  // T[d][k], pad keeps phase2 reads conflict-free
  const int k0 = blockIdx.x * 64;
  const int b = blockIdx.y;
  const int t = threadIdx.x;
#pragma unroll
  for (int it = 0; it < 4; ++it) {
    int kr = (t >> 4) + it * 16;
    int d4 = (t & 15) * 4;
    float4 f = *(const float4*)&X[((size_t)b * NN + k0 + kr) * DDIM + d4];
    T[d4 + 0][kr] = f2bf(f.x);
    T[d4 + 1][kr] = f2bf(f.y);
    T[d4 + 2][kr] = f2bf(f.z);
    T[d4 + 3][kr] = f2bf(f.w);
  }
  __syncthreads();
#pragma unroll
  for (int it = 0; it < 2; ++it) {
    int d = (t >> 3) + it * 32;
    int kc = (t & 7) * 8;
    *(uint4*)&XT[((size_t)b * DDIM + d) * NN + k0 + kc] = *(uint4*)&T[d][kc];
  }
}

// ---------------- chain GEMM: out = [add +] Aop * Bop, split 3-term --------
struct GemmJob {
  const u16* Ahi; const u16* Alo;     // A row-major MxK
  const u16* Bhi; const u16* Blo;     // B col-major: (k,n) at [n*NN+k]
  const float* addF;                  // optional fp32 additive init
  const u16* addHi; const u16* addLo; // optional split additive init
  u16* outRmHi; u16* outRmLo;         // optional row-major out
  u16* outCmHi; u16* outCmLo;         // optional col-major out
};
struct GemmJobs { GemmJob j[5]; };

__global__ __launch_bounds__(256, 2) void chain_gemm(GemmJobs jobs) {
  GemmJob jb = jobs.j[blockIdx.z];
  __shared__ u16 AlH[8192], AlL[8192], BlH[8192], BlL[8192];  // 64 KB exactly
  const int t = threadIdx.x, wave = t >> 6, lane = t & 63;
  const int wm = wave >> 1, wn = wave & 1;
  const int lm = lane & 15, q = lane >> 4;
  const int bm = blockIdx.x * 128, bn = blockIdx.y * 128;
  floatx4 acc[4][4] = {};

  for (int kt = 0; kt < 16; ++kt) {
    __syncthreads();
    stage_tile(jb.Ahi + (size_t)bm * NN + kt * 64, AlH, wave, lane);
    stage_tile(jb.Alo + (size_t)bm * NN + kt * 64, AlL, wave, lane);
    stage_tile(jb.Bhi + (size_t)bn * NN + kt * 64, BlH, wave, lane);
    stage_tile(jb.Blo + (size_t)bn * NN + kt * 64, BlL, wave, lane);
    __syncthreads();
#pragma unroll
    for (int ks = 0; ks < 2; ++ks) {
      const int st = ((ks * 4 + q) ^ (lm & 7)) * 8;
      bf16x8 bh[4], bl[4];
#pragma unroll
      for (int ni = 0; ni < 4; ++ni) {
        int rowb = (wn * 64 + ni * 16 + lm) * 64;
        bh[ni] = *(const bf16x8*)&BlH[rowb + st];
        bl[ni] = *(const bf16x8*)&BlL[rowb + st];
      }
#pragma unroll
      for (int mi = 0; mi < 4; ++mi) {
        int rowa = (wm * 64 + mi * 16 + lm) * 64;
        bf16x8 ah = *(const bf16x8*)&AlH[rowa + st];
        bf16x8 al = *(const bf16x8*)&AlL[rowa + st];
#pragma unroll
        for (int ni = 0; ni < 4; ++ni) {
          acc[mi][ni] = __builtin_amdgcn_mfma_f32_16x16x32_bf16(ah, bh[ni], acc[mi][ni], 0, 0, 0);
          acc[mi][ni] = __builtin_amdgcn_mfma_f32_16x16x32_bf16(ah, bl[ni], acc[mi][ni], 0, 0, 0);
          acc[mi][ni] = __builtin_amdgcn_mfma_f32_16x16x32_bf16(al, bh[ni], acc[mi][ni], 0, 0, 0);
        }
      }
    }
  }

#pragma unroll
  for (int mi = 0; mi < 4; ++mi)
#pragma unroll
    for (int ni = 0; ni < 4; ++ni)
#pragma unroll
      for (int r = 0; r < 4; ++r) {
        int row = bm + wm * 64 + mi * 16 + q * 4 + r;
        int col = bn + wn * 64 + ni * 16 + lm;
        size_t rm = (size_t)row * NN + col;
        float v = acc[mi][ni][r];
        if (jb.addF)  v += jb.addF[rm];
        if (jb.addHi) v += bf2f(jb.addHi[rm]) + bf2f(jb.addLo[rm]);
        u16 h = f2bf(v);
        u16 l = f2bf(v - bf2f(h));
        if (jb.outRmHi) { jb.outRmHi[rm] = h; jb.outRmLo[rm] = l; }
        if (jb.outCmHi) {
          size_t cm = (size_t)col * NN + row;
          jb.outCmHi[cm] = h; jb.outCmLo[cm] = l;
        }
      }
}

// ---------------- apply: out'[1024, 8192] = A @ XT^T (plain bf16) ----------
__global__ __launch_bounds__(256, 2) void apply_gemm(const u16* __restrict__ A,
                                                     const u16* __restrict__ XT,
                                                     float* __restrict__ out) {
  __shared__ u16 AlH[8192], Bt[8192];  // 32 KB
  const int t = threadIdx.x, wave = t >> 6, lane = t & 63;
  const int wm = wave >> 1, wn = wave & 1;
  const int lm = lane & 15, q = lane >> 4;
  const int bm = blockIdx.x * 128, bn = blockIdx.y * 128;
  floatx4 acc[4][4] = {};

  for (int kt = 0; kt < 16; ++kt) {
    __syncthreads();
    stage_tile(A + (size_t)bm * NN + kt * 64, AlH, wave, lane);
    stage_tile(XT + (size_t)bn * NN + kt * 64, Bt, wave, lane);
    __syncthreads();
#pragma unroll
    for (int ks = 0; ks < 2; ++ks) {
      const int st = ((ks * 4 + q) ^ (lm & 7)) * 8;
      bf16x8 bb[4];
#pragma unroll
      for (int ni = 0; ni < 4; ++ni)
        bb[ni] = *(const bf16x8*)&Bt[(wn * 64 + ni * 16 + lm) * 64 + st];
#pragma unroll
      for (int mi = 0; mi < 4; ++mi) {
        bf16x8 ah = *(const bf16x8*)&AlH[(wm * 64 + mi * 16 + lm) * 64 + st];
#pragma unroll
        for (int ni = 0; ni < 4; ++ni)
          acc[mi][ni] = __builtin_amdgcn_mfma_f32_16x16x32_bf16(ah, bb[ni], acc[mi][ni], 0, 0, 0);
      }
    }
  }

#pragma unroll
  for (int mi = 0; mi < 4; ++mi)
#pragma unroll
    for (int ni = 0; ni < 4; ++ni)
#pragma unroll
      for (int r = 0; r < 4; ++r) {
        int row = bm + wm * 64 + mi * 16 + q * 4 + r;
        int col = bn + wn * 64 + ni * 16 + lm;
        int b = col >> 6, d = col & 63;
        out[((size_t)b * NN + row) * DDIM + d] = acc[mi][ni][r];
      }
}

extern "C" void kernel_launch(void* const* d_in, const int* in_sizes, int n_in,
                              void* d_out, int out_size, void* d_ws, size_t ws_size,
                              hipStream_t stream) {
  const float* nodes  = (const float*)d_in[0];  // [128,1024,64]
  const float* weight = (const float*)d_in[1];  // [8,1024,1024]
  const float* gs     = (const float*)d_in[2];  // [1024,1024]
  float* out = (float*)d_out;
  u16* ws = (u16*)d_ws;
  const size_t MB = (size_t)NN * NN;
  auto buf = [&](int i) -> u16* { return ws + (size_t)i * MB; };
  // slots: 0,1 S rm hi/lo | 2,3 S cm hi/lo | 4..11 W1,W3,W5,W7 rm hi/lo
  // 12..19 U0..U3 | 20..23 S2 rm+cm | 24..27 V0,V1 | 28,29 S4 cm | 30,31 A
  // XT (16 MB) overlays slots 0..7 AFTER chain L1 consumed them. Total 64 MB.

  SplitJobs sj{};
  sj.j[0] = { gs,              buf(0),  buf(1),  buf(2), buf(3) };
  sj.j[1] = { weight + 1 * MB, buf(4),  buf(5),  nullptr, nullptr };
  sj.j[2] = { weight + 3 * MB, buf(6),  buf(7),  nullptr, nullptr };
  sj.j[3] = { weight + 5 * MB, buf(8),  buf(9),  nullptr, nullptr };
  sj.j[4] = { weight + 7 * MB, buf(10), buf(11), nullptr, nullptr };
  split_kernel<<<dim3(NN * NN / 1024, 1, 5), 256, 0, stream>>>(sj);

  GemmJobs g1{};
  g1.j[0] = { buf(0), buf(1), buf(2), buf(3), nullptr, nullptr, nullptr,
              buf(20), buf(21), buf(22), buf(23) };            // S2 rm+cm
  g1.j[1] = { buf(4),  buf(5),  buf(2), buf(3), weight + 0 * MB, nullptr, nullptr,
              buf(12), buf(13), nullptr, nullptr };            // U0
  g1.j[2] = { buf(6),  buf(7),  buf(2), buf(3), weight + 2 * MB, nullptr, nullptr,
              buf(14), buf(15), nullptr, nullptr };            // U1
  g1.j[3] = { buf(8),  buf(9),  buf(2), buf(3), weight + 4 * MB, nullptr, nullptr,
              buf(16), buf(17), nullptr, nullptr };            // U2
  g1.j[4] = { buf(10), buf(11), buf(2), buf(3), weight + 6 * MB, nullptr, nullptr,
              buf(18), buf(19), nullptr, nullptr };            // U3
  chain_gemm<<<dim3(8, 8, 5), 256, 0, stream>>>(g1);

  // XT reuses slots 0..7 (dead after L1)
  u16* XT = buf(0);
  transpose_x<<<dim3(16, NBATCH), 256, 0, stream>>>(nodes, XT);

  GemmJobs g2{};
  g2.j[0] = { buf(20), buf(21), buf(22), buf(23), nullptr, nullptr, nullptr,
              nullptr, nullptr, buf(28), buf(29) };            // S4 cm
  g2.j[1] = { buf(14), buf(15), buf(22), buf(23), nullptr, buf(12), buf(13),
              buf(24), buf(25), nullptr, nullptr };            // V0 = U0 + U1*S2
  g2.j[2] = { buf(18), buf(19), buf(22), buf(23), nullptr, buf(16), buf(17),
              buf(26), buf(27), nullptr, nullptr };            // V1 = U2 + U3*S2
  chain_gemm<<<dim3(8, 8, 3), 256, 0, stream>>>(g2);

  GemmJobs g3{};
  g3.j[0] = { buf(26), buf(27), buf(28), buf(29), nullptr, buf(24), buf(25),
              buf(30), buf(31), nullptr, nullptr };            // A = V0 + V1*S4
  chain_gemm<<<dim3(8, 8, 1), 256, 0, stream>>>(g3);

  apply_gemm<<<dim3(8, 64), 256, 0, stream>>>(buf(30), XT, out);
}

// Round 3
// 251.841 us; speedup vs baseline: 1.2912x; 1.1861x over previous
//
#include <hip/hip_runtime.h>
#include <stdint.h>

// graphConv: out[b] = (sum_k W_k S^k) @ X_b ; B=128, N=1024, D=64, K=8
//
// Chain (depth 3, split-bf16 3-term for ~fp32 accuracy):
//   L1: S2 = S*S ; U_j = W_{2j} + W_{2j+1}*S (j=0..3)   64x128 tiles, 640 blk
//   L2: S4 = S2*S2 ; V0 = U0+U1*S2 ; V1 = U2+U3*S2      64x64 tiles,  768 blk
//   L3: A  = V0 + V1*S4  (split-K=4 fp32 partials)      64x64 tiles, 1024 blk
//   combine: A_hi = V0 + sum partials
// Apply: out' = A @ XT as ONE 1024x8192x1024 bf16 GEMM (128x128 tiles).
// LDS: BK=64 rows of 128B, 16B chunks XOR-swizzled by row&7 (verified
// conflict-free R2), staged via global_load_lds width=16.

#define NN 1024
#define NBATCH 128
#define DDIM 64

typedef float floatx4 __attribute__((ext_vector_type(4)));
typedef __bf16 bf16x8 __attribute__((ext_vector_type(8)));
typedef unsigned short u16;

__device__ __forceinline__ u16 f2bf(float f) {
  union { float f; uint32_t u; } v; v.f = f;
  uint32_t u = v.u;
  return (u16)((u + 0x7fffu + ((u >> 16) & 1u)) >> 16);  // RNE
}
__device__ __forceinline__ float bf2f(u16 h) {
  union { float f; uint32_t u; } v; v.u = ((uint32_t)h) << 16;
  return v.f;
}

__device__ __forceinline__ void gll16(const void* g, void* l) {
  __builtin_amdgcn_global_load_lds(
      (const __attribute__((address_space(1))) void*)g,
      (__attribute__((address_space(3))) void*)l, 16, 0, 0);
}

// Stage ROWS x 64 u16 tile (row stride NN) into linear LDS, 16B chunks
// XOR-swizzled by row&7. Conflict-free on DMA write and ds_read_b128.
template <int ROWS>
__device__ __forceinline__ void stage_tile(const u16* __restrict__ g, u16* lds,
                                           int wave, int lane) {
  const int r = lane >> 3, c = lane & 7;
  const int sw = (c ^ r) * 8;
#pragma unroll
  for (int i = 0; i < ROWS / 32; ++i) {
    const int rb = wave * (ROWS / 4) + i * 8;
    gll16(g + (size_t)(rb + r) * NN + sw, lds + rb * 64);
  }
}

// ---------------- split fp32 -> bf16 hi/lo --------------------------------
struct SplitJob {
  const float* src;
  u16* rmHi; u16* rmLo;
  u16* cmHi; u16* cmLo;  // may be null
};
struct SplitJobs { SplitJob j[5]; };

__global__ __launch_bounds__(256) void split_kernel(SplitJobs jobs) {
  SplitJob jb = jobs.j[blockIdx.z];
  int idx4 = blockIdx.x * 256 + threadIdx.x;
  int e = idx4 * 4;
  int row = e >> 10;
  int col = e & (NN - 1);
  float4 f = ((const float4*)jb.src)[idx4];
  float fv[4] = {f.x, f.y, f.z, f.w};
  u16 hi[4], lo[4];
#pragma unroll
  for (int i = 0; i < 4; ++i) {
    hi[i] = f2bf(fv[i]);
    lo[i] = f2bf(fv[i] - bf2f(hi[i]));
  }
  uint2 ph, pl;
  ph.x = (uint32_t)hi[0] | ((uint32_t)hi[1] << 16);
  ph.y = (uint32_t)hi[2] | ((uint32_t)hi[3] << 16);
  pl.x = (uint32_t)lo[0] | ((uint32_t)lo[1] << 16);
  pl.y = (uint32_t)lo[2] | ((uint32_t)lo[3] << 16);
  *(uint2*)&jb.rmHi[e] = ph;
  *(uint2*)&jb.rmLo[e] = pl;
  if (jb.cmHi) {
#pragma unroll
    for (int i = 0; i < 4; ++i) {
      jb.cmHi[(size_t)(col + i) * NN + row] = hi[i];
      jb.cmLo[(size_t)(col + i) * NN + row] = lo[i];
    }
  }
}

// ---------------- transpose X [B,K,D] fp32 -> XT [B*D, K] bf16 -------------
__global__ __launch_bounds__(256) void transpose_x(const float* __restrict__ X,
                                                   u16* __restrict__ XT) {
  __shared__ u16 T[64][72];
  const int k0 = blockIdx.x * 64;
  const int b = blockIdx.y;
  const int t = threadIdx.x;
#pragma unroll
  for (int it = 0; it < 4; ++it) {
    int kr = (t >> 4) + it * 16;
    int d4 = (t & 15) * 4;
    float4 f = *(const float4*)&X[((size_t)b * NN + k0 + kr) * DDIM + d4];
    T[d4 + 0][kr] = f2bf(f.x);
    T[d4 + 1][kr] = f2bf(f.y);
    T[d4 + 2][kr] = f2bf(f.z);
    T[d4 + 3][kr] = f2bf(f.w);
  }
  __syncthreads();
#pragma unroll
  for (int it = 0; it < 2; ++it) {
    int d = (t >> 3) + it * 32;
    int kc = (t & 7) * 8;
    *(uint4*)&XT[((size_t)b * DDIM + d) * NN + k0 + kc] = *(uint4*)&T[d][kc];
  }
}

// ---------------- chain GEMM: out = [add +] Aop * Bop, split 3-term --------
struct GemmJob {
  const u16* Ahi; const u16* Alo;     // A row-major MxK
  const u16* Bhi; const u16* Blo;     // B col-major: (k,n) at [n*NN+k]
  const float* addF;                  // optional fp32 additive init
  const u16* addHi; const u16* addLo; // optional split additive init
  u16* outRmHi; u16* outRmLo;         // optional row-major out
  u16* outCmHi; u16* outCmLo;         // optional col-major out
};
struct GemmJobs { GemmJob j[5]; };

template <int BM, int BN>
__global__ __launch_bounds__(256, 2) void chain_gemm(GemmJobs jobs) {
  GemmJob jb = jobs.j[blockIdx.z];
  __shared__ u16 AlH[BM * 64], AlL[BM * 64], BlH[BN * 64], BlL[BN * 64];
  const int t = threadIdx.x, wave = t >> 6, lane = t & 63;
  const int wm = wave >> 1, wn = wave & 1;
  const int lm = lane & 15, q = lane >> 4;
  const int bm = blockIdx.x * BM, bn = blockIdx.y * BN;
  constexpr int MI = BM / 32, NI = BN / 32;
  floatx4 acc[MI][NI] = {};

  for (int kt = 0; kt < 16; ++kt) {
    __syncthreads();
    stage_tile<BM>(jb.Ahi + (size_t)bm * NN + kt * 64, AlH, wave, lane);
    stage_tile<BM>(jb.Alo + (size_t)bm * NN + kt * 64, AlL, wave, lane);
    stage_tile<BN>(jb.Bhi + (size_t)bn * NN + kt * 64, BlH, wave, lane);
    stage_tile<BN>(jb.Blo + (size_t)bn * NN + kt * 64, BlL, wave, lane);
    __syncthreads();
#pragma unroll
    for (int ks = 0; ks < 2; ++ks) {
      const int st = ((ks * 4 + q) ^ (lm & 7)) * 8;
      bf16x8 bh[NI], bl[NI];
#pragma unroll
      for (int ni = 0; ni < NI; ++ni) {
        int rowb = (wn * (BN / 2) + ni * 16 + lm) * 64;
        bh[ni] = *(const bf16x8*)&BlH[rowb + st];
        bl[ni] = *(const bf16x8*)&BlL[rowb + st];
      }
#pragma unroll
      for (int mi = 0; mi < MI; ++mi) {
        int rowa = (wm * (BM / 2) + mi * 16 + lm) * 64;
        bf16x8 ah = *(const bf16x8*)&AlH[rowa + st];
        bf16x8 al = *(const bf16x8*)&AlL[rowa + st];
#pragma unroll
        for (int ni = 0; ni < NI; ++ni) {
          acc[mi][ni] = __builtin_amdgcn_mfma_f32_16x16x32_bf16(ah, bh[ni], acc[mi][ni], 0, 0, 0);
          acc[mi][ni] = __builtin_amdgcn_mfma_f32_16x16x32_bf16(ah, bl[ni], acc[mi][ni], 0, 0, 0);
          acc[mi][ni] = __builtin_amdgcn_mfma_f32_16x16x32_bf16(al, bh[ni], acc[mi][ni], 0, 0, 0);
        }
      }
    }
  }

#pragma unroll
  for (int mi = 0; mi < MI; ++mi)
#pragma unroll
    for (int ni = 0; ni < NI; ++ni)
#pragma unroll
      for (int r = 0; r < 4; ++r) {
        int row = bm + wm * (BM / 2) + mi * 16 + q * 4 + r;
        int col = bn + wn * (BN / 2) + ni * 16 + lm;
        size_t rm = (size_t)row * NN + col;
        float v = acc[mi][ni][r];
        if (jb.addF)  v += jb.addF[rm];
        if (jb.addHi) v += bf2f(jb.addHi[rm]) + bf2f(jb.addLo[rm]);
        u16 h = f2bf(v);
        u16 l = f2bf(v - bf2f(h));
        if (jb.outRmHi) { jb.outRmHi[rm] = h; jb.outRmLo[rm] = l; }
        if (jb.outCmHi) {
          size_t cm = (size_t)col * NN + row;
          jb.outCmHi[cm] = h; jb.outCmLo[cm] = l;
        }
      }
}

// ---------------- split-K chain GEMM (fp32 partials, z = K-chunk) ----------
struct SplitkJob {
  const u16* Ahi; const u16* Alo;
  const u16* Bhi; const u16* Blo;
  float* part;  // KSPLIT partial matrices, each NN*NN fp32
};

template <int BM, int BN, int KSPLIT>
__global__ __launch_bounds__(256, 2) void chain_splitk(SplitkJob jb) {
  __shared__ u16 AlH[BM * 64], AlL[BM * 64], BlH[BN * 64], BlL[BN * 64];
  const int t = threadIdx.x, wave = t >> 6, lane = t & 63;
  const int wm = wave >> 1, wn = wave & 1;
  const int lm = lane & 15, q = lane >> 4;
  const int bm = blockIdx.x * BM, bn = blockIdx.y * BN;
  const int z = blockIdx.z;
  constexpr int MI = BM / 32, NI = BN / 32, KT = 16 / KSPLIT;
  floatx4 acc[MI][NI] = {};

  for (int kk = 0; kk < KT; ++kk) {
    int kt = z * KT + kk;
    __syncthreads();
    stage_tile<BM>(jb.Ahi + (size_t)bm * NN + kt * 64, AlH, wave, lane);
    stage_tile<BM>(jb.Alo + (size_t)bm * NN + kt * 64, AlL, wave, lane);
    stage_tile<BN>(jb.Bhi + (size_t)bn * NN + kt * 64, BlH, wave, lane);
    stage_tile<BN>(jb.Blo + (size_t)bn * NN + kt * 64, BlL, wave, lane);
    __syncthreads();
#pragma unroll
    for (int ks = 0; ks < 2; ++ks) {
      const int st = ((ks * 4 + q) ^ (lm & 7)) * 8;
      bf16x8 bh[NI], bl[NI];
#pragma unroll
      for (int ni = 0; ni < NI; ++ni) {
        int rowb = (wn * (BN / 2) + ni * 16 + lm) * 64;
        bh[ni] = *(const bf16x8*)&BlH[rowb + st];
        bl[ni] = *(const bf16x8*)&BlL[rowb + st];
      }
#pragma unroll
      for (int mi = 0; mi < MI; ++mi) {
        int rowa = (wm * (BM / 2) + mi * 16 + lm) * 64;
        bf16x8 ah = *(const bf16x8*)&AlH[rowa + st];
        bf16x8 al = *(const bf16x8*)&AlL[rowa + st];
#pragma unroll
        for (int ni = 0; ni < NI; ++ni) {
          acc[mi][ni] = __builtin_amdgcn_mfma_f32_16x16x32_bf16(ah, bh[ni], acc[mi][ni], 0, 0, 0);
          acc[mi][ni] = __builtin_amdgcn_mfma_f32_16x16x32_bf16(ah, bl[ni], acc[mi][ni], 0, 0, 0);
          acc[mi][ni] = __builtin_amdgcn_mfma_f32_16x16x32_bf16(al, bh[ni], acc[mi][ni], 0, 0, 0);
        }
      }
    }
  }

  float* p = jb.part + (size_t)z * NN * NN;
#pragma unroll
  for (int mi = 0; mi < MI; ++mi)
#pragma unroll
    for (int ni = 0; ni < NI; ++ni)
#pragma unroll
      for (int r = 0; r < 4; ++r) {
        int row = bm + wm * (BM / 2) + mi * 16 + q * 4 + r;
        int col = bn + wn * (BN / 2) + ni * 16 + lm;
        p[(size_t)row * NN + col] = acc[mi][ni][r];
      }
}

// ---------------- combine: A_hi = V0(hi+lo) + sum_z partials ---------------
__global__ __launch_bounds__(256) void combine_A(const float* __restrict__ parts,
                                                 const u16* __restrict__ v0h,
                                                 const u16* __restrict__ v0l,
                                                 u16* __restrict__ aHi) {
  int e = (blockIdx.x * 256 + threadIdx.x) * 4;
  float4 s = *(const float4*)&parts[e];
#pragma unroll
  for (int z = 1; z < 4; ++z) {
    float4 p = *(const float4*)&parts[(size_t)z * NN * NN + e];
    s.x += p.x; s.y += p.y; s.z += p.z; s.w += p.w;
  }
  uint2 h = *(const uint2*)&v0h[e];
  uint2 l = *(const uint2*)&v0l[e];
  float v[4];
  v[0] = s.x + bf2f((u16)h.x)         + bf2f((u16)l.x);
  v[1] = s.y + bf2f((u16)(h.x >> 16)) + bf2f((u16)(l.x >> 16));
  v[2] = s.z + bf2f((u16)h.y)         + bf2f((u16)l.y);
  v[3] = s.w + bf2f((u16)(h.y >> 16)) + bf2f((u16)(l.y >> 16));
  uint2 o;
  o.x = (uint32_t)f2bf(v[0]) | ((uint32_t)f2bf(v[1]) << 16);
  o.y = (uint32_t)f2bf(v[2]) | ((uint32_t)f2bf(v[3]) << 16);
  *(uint2*)&aHi[e] = o;
}

// ---------------- apply: out'[1024, 8192] = A @ XT^T (plain bf16) ----------
__global__ __launch_bounds__(256, 2) void apply_gemm(const u16* __restrict__ A,
                                                     const u16* __restrict__ XT,
                                                     float* __restrict__ out) {
  __shared__ u16 AlH[8192], Bt[8192];
  const int t = threadIdx.x, wave = t >> 6, lane = t & 63;
  const int wm = wave >> 1, wn = wave & 1;
  const int lm = lane & 15, q = lane >> 4;
  const int bm = blockIdx.x * 128, bn = blockIdx.y * 128;
  floatx4 acc[4][4] = {};

  for (int kt = 0; kt < 16; ++kt) {
    __syncthreads();
    stage_tile<128>(A + (size_t)bm * NN + kt * 64, AlH, wave, lane);
    stage_tile<128>(XT + (size_t)bn * NN + kt * 64, Bt, wave, lane);
    __syncthreads();
#pragma unroll
    for (int ks = 0; ks < 2; ++ks) {
      const int st = ((ks * 4 + q) ^ (lm & 7)) * 8;
      bf16x8 bb[4];
#pragma unroll
      for (int ni = 0; ni < 4; ++ni)
        bb[ni] = *(const bf16x8*)&Bt[(wn * 64 + ni * 16 + lm) * 64 + st];
#pragma unroll
      for (int mi = 0; mi < 4; ++mi) {
        bf16x8 ah = *(const bf16x8*)&AlH[(wm * 64 + mi * 16 + lm) * 64 + st];
#pragma unroll
        for (int ni = 0; ni < 4; ++ni)
          acc[mi][ni] = __builtin_amdgcn_mfma_f32_16x16x32_bf16(ah, bb[ni], acc[mi][ni], 0, 0, 0);
      }
    }
  }

#pragma unroll
  for (int mi = 0; mi < 4; ++mi)
#pragma unroll
    for (int ni = 0; ni < 4; ++ni)
#pragma unroll
      for (int r = 0; r < 4; ++r) {
        int row = bm + wm * 64 + mi * 16 + q * 4 + r;
        int col = bn + wn * 64 + ni * 16 + lm;
        int b = col >> 6, d = col & 63;
        out[((size_t)b * NN + row) * DDIM + d] = acc[mi][ni][r];
      }
}

extern "C" void kernel_launch(void* const* d_in, const int* in_sizes, int n_in,
                              void* d_out, int out_size, void* d_ws, size_t ws_size,
                              hipStream_t stream) {
  const float* nodes  = (const float*)d_in[0];  // [128,1024,64]
  const float* weight = (const float*)d_in[1];  // [8,1024,1024]
  const float* gs     = (const float*)d_in[2];  // [1024,1024]
  float* out = (float*)d_out;
  u16* ws = (u16*)d_ws;
  const size_t MB = (size_t)NN * NN;
  auto buf = [&](int i) -> u16* { return ws + (size_t)i * MB; };
  // slots (2 MB each): 0,1 S rm hi/lo | 2,3 S cm hi/lo | 4..11 W1,3,5,7 hi/lo
  // 12..19 U0..U3 (dead after L2 -> reused as 16 MB fp32 L3 partials)
  // 20..23 S2 rm+cm | 24..27 V0,V1 | 28,29 S4 cm | 30 A hi
  // XT (16 MB) overlays 0..7 after L1. Total 64 MB.

  SplitJobs sj{};
  sj.j[0] = { gs,              buf(0),  buf(1),  buf(2), buf(3) };
  sj.j[1] = { weight + 1 * MB, buf(4),  buf(5),  nullptr, nullptr };
  sj.j[2] = { weight + 3 * MB, buf(6),  buf(7),  nullptr, nullptr };
  sj.j[3] = { weight + 5 * MB, buf(8),  buf(9),  nullptr, nullptr };
  sj.j[4] = { weight + 7 * MB, buf(10), buf(11), nullptr, nullptr };
  split_kernel<<<dim3(NN * NN / 1024, 1, 5), 256, 0, stream>>>(sj);

  GemmJobs g1{};
  g1.j[0] = { buf(0), buf(1), buf(2), buf(3), nullptr, nullptr, nullptr,
              buf(20), buf(21), buf(22), buf(23) };            // S2 rm+cm
  g1.j[1] = { buf(4),  buf(5),  buf(2), buf(3), weight + 0 * MB, nullptr, nullptr,
              buf(12), buf(13), nullptr, nullptr };            // U0
  g1.j[2] = { buf(6),  buf(7),  buf(2), buf(3), weight + 2 * MB, nullptr, nullptr,
              buf(14), buf(15), nullptr, nullptr };            // U1
  g1.j[3] = { buf(8),  buf(9),  buf(2), buf(3), weight + 4 * MB, nullptr, nullptr,
              buf(16), buf(17), nullptr, nullptr };            // U2
  g1.j[4] = { buf(10), buf(11), buf(2), buf(3), weight + 6 * MB, nullptr, nullptr,
              buf(18), buf(19), nullptr, nullptr };            // U3
  chain_gemm<64, 128><<<dim3(16, 8, 5), 256, 0, stream>>>(g1);

  u16* XT = buf(0);  // reuses slots 0..7 (dead after L1)
  transpose_x<<<dim3(16, NBATCH), 256, 0, stream>>>(nodes, XT);

  GemmJobs g2{};
  g2.j[0] = { buf(20), buf(21), buf(22), buf(23), nullptr, nullptr, nullptr,
              nullptr, nullptr, buf(28), buf(29) };            // S4 cm
  g2.j[1] = { buf(14), buf(15), buf(22), buf(23), nullptr, buf(12), buf(13),
              buf(24), buf(25), nullptr, nullptr };            // V0 = U0 + U1*S2
  g2.j[2] = { buf(18), buf(19), buf(22), buf(23), nullptr, buf(16), buf(17),
              buf(26), buf(27), nullptr, nullptr };            // V1 = U2 + U3*S2
  chain_gemm<64, 64><<<dim3(16, 16, 3), 256, 0, stream>>>(g2);

  // L3: A = V0 + V1*S4 via split-K=4 (partials overlay dead slots 12..19)
  float* parts = (float*)buf(12);
  SplitkJob sk{ buf(26), buf(27), buf(28), buf(29), parts };
  chain_splitk<64, 64, 4><<<dim3(16, 16, 4), 256, 0, stream>>>(sk);
  combine_A<<<dim3(NN * NN / 1024), 256, 0, stream>>>(parts, buf(24), buf(25), buf(30));

  apply_gemm<<<dim3(8, 64), 256, 0, stream>>>(buf(30), XT, out);
}